// Round 7
// baseline (222.295 us; speedup 1.0000x reference)
//
#include <hip/hip_runtime.h>

// TopologyNetwork: B=1024, N=5000, K=16, 9 levels.
// R7 = R6 with native _Float16 ext-vectors (ROCm __half2 API rejected the
// R6 overloads). Design:
//  - activations f16 [g][n][8 cols] (uint4 per node-row), ping-pong in d_ws.
//  - edges packed [l][n][k] u32 = (u16 idx | f16 w), per-node 4x uint4 loads
//    (streaming, L2-resident) -- NOT a per-block broadcast (R5 mistake).
//  - per level: block (h,g) stages col-group g's 80000 B prev-level slice
//    into LDS, then gathers via ds_read_b128; packed f16x2 FMA accumulate.
//  - grid 4 node-quarters x 128 col-groups, 640 thr -> 2 blocks/CU
//    (2 x 80000 B = 156 KiB of 160 KiB LDS).

#define TB 1024
#define TN 5000
#define TK 16
#define TLV 9
#define CPG 8                  // f16 cols per group (16 B per node-row)
#define NG  (TB / CPG)         // 128 col-groups
#define NH  4                  // node quarters per level
#define NPB (TN / NH)          // 1250 nodes per block
#define LT  640                // threads per level block (10 waves)

typedef unsigned int u32;
typedef unsigned short u16;
typedef _Float16 h2 __attribute__((ext_vector_type(2)));

__device__ __forceinline__ h2 u2h(u32 v) { return __builtin_bit_cast(h2, v); }
__device__ __forceinline__ u32 h2u(h2 h) { return __builtin_bit_cast(u32, h); }
__device__ __forceinline__ u32 packf(float a, float b) {
    h2 h; h.x = (_Float16)a; h.y = (_Float16)b;
    return h2u(h);
}

// ---- pack edges: idx i32 + w f32, both [l][n][k] -> pe u32 [l][n][k] ----
__global__ __launch_bounds__(256) void k_pack(
    const int* __restrict__ idx, const float* __restrict__ w,
    u32* __restrict__ pe)
{
    const int j = blockIdx.x * 256 + threadIdx.x;
    if (j < TLV * TN * TK) {
        const u32 s = (u32)idx[j] & 0xffffu;
        h2 hw; hw.x = (_Float16)w[j]; hw.y = (_Float16)0.0f;
        pe[j] = s | (h2u(hw) << 16);
    }
}

// ---- transpose-in: x f32 [B,N] -> act f16 [NG][TN][CPG] (uint4 rows) ----
__global__ __launch_bounds__(256) void k_tin(
    const float* __restrict__ x, uint4* __restrict__ act)
{
    const int g = blockIdx.x;
    for (int n = threadIdx.x; n < TN; n += 256) {
        const float* xp = x + (size_t)(g * CPG) * TN + n;
        uint4 v;
        v.x = packf(xp[0],              xp[(size_t)TN]);
        v.y = packf(xp[2 * (size_t)TN], xp[3 * (size_t)TN]);
        v.z = packf(xp[4 * (size_t)TN], xp[5 * (size_t)TN]);
        v.w = packf(xp[6 * (size_t)TN], xp[7 * (size_t)TN]);
        act[(size_t)g * TN + n] = v;
    }
}

// ---- one DAG level: stage slice in LDS, gather via ds_read_b128 ----
__global__ __launch_bounds__(LT) void k_level(
    const uint4* __restrict__ in,    // [NG][TN]
    uint4* __restrict__ outa,        // [NG][TN]
    const uint4* __restrict__ pe,    // [TN][4] packed edges this level
    const float* __restrict__ bias)  // [TN] this level
{
    __shared__ uint4 lds[TN];        // 80000 B slice of prev level
    const int g = blockIdx.y;        // col-group
    const int h = blockIdx.x;        // node quarter

    const uint4* src = in + (size_t)g * TN;
    for (int j = threadIdx.x; j < TN; j += LT) lds[j] = src[j];
    __syncthreads();

    uint4* dst = outa + (size_t)g * TN;
    const int n0 = h * NPB;
    for (int n = n0 + threadIdx.x; n < n0 + NPB; n += LT) {
        const uint4 e0 = pe[n * 4 + 0];
        const uint4 e1 = pe[n * 4 + 1];
        const uint4 e2 = pe[n * 4 + 2];
        const uint4 e3 = pe[n * 4 + 3];
        const u32 es[TK] = {e0.x, e0.y, e0.z, e0.w,
                            e1.x, e1.y, e1.z, e1.w,
                            e2.x, e2.y, e2.z, e2.w,
                            e3.x, e3.y, e3.z, e3.w};

        const float bvf = bias[n];
        h2 bb; bb.x = (_Float16)bvf; bb.y = (_Float16)bvf;
        h2 a0 = bb, a1 = bb, a2 = bb, a3 = bb;

        #pragma unroll
        for (int k = 0; k < TK; ++k) {
            const u32 e = es[k];
            const u32 s = e & 0xffffu;
            // replicate f16 w (bytes 2,3) into both halves
            const h2 w2 = u2h(__builtin_amdgcn_perm(e, e, 0x03020302u));
            const uint4 av = lds[s];                     // ds_read_b128
            a0 = w2 * u2h(av.x) + a0;                    // v_pk_fma_f16
            a1 = w2 * u2h(av.y) + a1;
            a2 = w2 * u2h(av.z) + a2;
            a3 = w2 * u2h(av.w) + a3;
        }

        // LeakyReLU(0.1) = max(x, 0.1*x) elementwise (negatives: 0.1x > x? no;
        // for x<0: 0.1x > x, so max(x, 0.1x) = 0.1x; for x>0: max = x). OK.
        h2 tenth; tenth.x = (_Float16)0.1f; tenth.y = (_Float16)0.1f;
        a0 = __builtin_elementwise_max(a0, a0 * tenth);
        a1 = __builtin_elementwise_max(a1, a1 * tenth);
        a2 = __builtin_elementwise_max(a2, a2 * tenth);
        a3 = __builtin_elementwise_max(a3, a3 * tenth);

        uint4 r;
        r.x = h2u(a0); r.y = h2u(a1); r.z = h2u(a2); r.w = h2u(a3);
        dst[n] = r;
    }
}

// ---- transpose-out: act f16 [NG][TN][CPG] -> out f32 [B,N] ----
__global__ __launch_bounds__(256) void k_tout(
    const uint4* __restrict__ act, float* __restrict__ out)
{
    const int g = blockIdx.x;
    for (int n = threadIdx.x; n < TN; n += 256) {
        const uint4 v = act[(size_t)g * TN + n];
        float* op = out + (size_t)(g * CPG) * TN + n;
        h2 h;
        h = u2h(v.x); op[0]              = (float)h.x; op[(size_t)TN]     = (float)h.y;
        h = u2h(v.y); op[2 * (size_t)TN] = (float)h.x; op[3 * (size_t)TN] = (float)h.y;
        h = u2h(v.z); op[4 * (size_t)TN] = (float)h.x; op[5 * (size_t)TN] = (float)h.y;
        h = u2h(v.w); op[6 * (size_t)TN] = (float)h.x; op[7 * (size_t)TN] = (float)h.y;
    }
}

extern "C" void kernel_launch(void* const* d_in, const int* in_sizes, int n_in,
                              void* d_out, int out_size, void* d_ws, size_t ws_size,
                              hipStream_t stream)
{
    const float* x       = (const float*)d_in[0];   // [B,N]
    const int*   src_idx = (const int*)  d_in[1];   // [LV,N,K]
    const float* weights = (const float*)d_in[2];   // [LV,N,K]
    const float* biases  = (const float*)d_in[3];   // [LV,N]
    float* out = (float*)d_out;                     // [B,N]

    uint4* actA = (uint4*)d_ws;                     // [NG][TN] = 10.24 MB
    uint4* actB = actA + (size_t)NG * TN;           // 10.24 MB
    u32*   pe   = (u32*)(actB + (size_t)NG * TN);   // [LV][TN][TK] = 2.88 MB

    // pack edges (elementwise, coalesced)
    {
        const int ne = TLV * TN * TK;
        hipLaunchKernelGGL(k_pack, dim3((ne + 255) / 256), dim3(256), 0, stream,
                           src_idx, weights, pe);
    }
    // x -> actA
    hipLaunchKernelGGL(k_tin, dim3(NG), dim3(256), 0, stream, x, actA);

    uint4* cur = actA;
    uint4* nxt = actB;
    for (int l = 0; l < TLV; ++l) {
        hipLaunchKernelGGL(k_level, dim3(NH, NG), dim3(LT), 0, stream,
                           cur, nxt,
                           (const uint4*)(pe + (size_t)l * TN * TK),
                           biases + (size_t)l * TN);
        uint4* tmp = cur; cur = nxt; nxt = tmp;
    }

    hipLaunchKernelGGL(k_tout, dim3(NG), dim3(256), 0, stream, cur, out);
}

// Round 8
// 181.599 us; speedup vs baseline: 1.2241x; 1.2241x over previous
//
#include <hip/hip_runtime.h>

// TopologyNetwork: B=1024, N=5000, K=16, 9 levels.
// R8: LDS-gather, R7 overheads removed:
//  - C=4 f16 cols/group -> NG=256 groups, grid=256, block=1024 (16 waves),
//    FULL N per block: slice staged once (40 KB), edges read once per group.
//  - block g -> XCD g%8 every level: level l's writer of group g and level
//    l+1's reader are the same XCD -> staging hits local L2.
//  - gather = one ds_read_b64 per edge (8 B node-row, 16 bank-classes ~2x).
//  - edges prepacked [l][panel64][k][lane] u32=(u16 idx|f16 w): every edge
//    load is a coalesced, 100%-utilized 256 B line; 16 dword loads/node.

#define TB 1024
#define TN 5000
#define TK 16
#define TLV 9
#define CPG 4                   // f16 cols per group (8 B per node-row)
#define NG  (TB / CPG)          // 256 col-groups = grid
#define LT  1024                // threads per level block (16 waves)
#define NPANEL ((TN + 63) / 64) // 79 panels of 64 nodes
#define PEL (NPANEL * TK * 64)  // u32 per level in packed-edge array

typedef unsigned int u32;
typedef unsigned short u16;
typedef _Float16 h2 __attribute__((ext_vector_type(2)));

__device__ __forceinline__ h2 u2h(u32 v) { return __builtin_bit_cast(h2, v); }
__device__ __forceinline__ u32 h2u(h2 h) { return __builtin_bit_cast(u32, h); }
__device__ __forceinline__ u32 packf(float a, float b) {
    h2 h; h.x = (_Float16)a; h.y = (_Float16)b;
    return h2u(h);
}

// ---- pack edges: idx i32 + w f32 [l][n][k] -> pe u32 [l][n>>6][k][n&63] ----
__global__ __launch_bounds__(256) void k_pack(
    const int* __restrict__ idx, const float* __restrict__ w,
    u32* __restrict__ pe)
{
    const int j = blockIdx.x * 256 + threadIdx.x;
    if (j < TLV * TN * TK) {
        const int l = j / (TN * TK);
        const int r = j % (TN * TK);
        const int n = r / TK;
        const int k = r % TK;
        h2 hw; hw.x = (_Float16)w[j]; hw.y = (_Float16)0.0f;
        const u32 v = ((u32)idx[j] & 0xffffu) | (h2u(hw) << 16);
        pe[(size_t)l * PEL + (n >> 6) * (TK * 64) + k * 64 + (n & 63)] = v;
    }
}

// ---- transpose-in: x f32 [B,N] -> act f16 [NG][TN][CPG] (uint2 rows) ----
__global__ __launch_bounds__(256) void k_tin(
    const float* __restrict__ x, uint2* __restrict__ act)
{
    const int g = blockIdx.x;
    const float* xp0 = x + (size_t)(g * CPG + 0) * TN;
    const float* xp1 = x + (size_t)(g * CPG + 1) * TN;
    const float* xp2 = x + (size_t)(g * CPG + 2) * TN;
    const float* xp3 = x + (size_t)(g * CPG + 3) * TN;
    uint2* dst = act + (size_t)g * TN;
    for (int n = threadIdx.x; n < TN; n += 256) {
        uint2 v;
        v.x = packf(xp0[n], xp1[n]);
        v.y = packf(xp2[n], xp3[n]);
        dst[n] = v;
    }
}

// ---- one DAG level ----
__global__ __launch_bounds__(LT) void k_level(
    const uint2* __restrict__ in,    // [NG][TN]
    uint2* __restrict__ outa,        // [NG][TN]
    const u32* __restrict__ pe,      // [NPANEL][TK][64] this level
    const float* __restrict__ bias)  // [TN] this level
{
    __shared__ uint2 lds[TN];        // 40000 B slice of prev level
    const int g = blockIdx.x;
    const int t = threadIdx.x;

    const uint2* src = in + (size_t)g * TN;
    for (int j = t; j < TN; j += LT) lds[j] = src[j];   // coalesced b64
    __syncthreads();

    uint2* dst = outa + (size_t)g * TN;
    for (int n = t; n < TN; n += LT) {
        const u32* ep = pe + (n >> 6) * (TK * 64) + (n & 63);
        const float bvf = bias[n];
        h2 bb; bb.x = (_Float16)bvf; bb.y = (_Float16)bvf;
        h2 a01 = bb, a23 = bb;

        #pragma unroll
        for (int k = 0; k < TK; ++k) {
            const u32 e = ep[k * 64];                    // coalesced 256 B line
            const u32 s = e & 0xffffu;
            const h2 w2 = u2h(__builtin_amdgcn_perm(e, e, 0x03020302u));
            const uint2 av = lds[s];                     // ds_read_b64, random row
            a01 = w2 * u2h(av.x) + a01;                  // v_pk_fma_f16
            a23 = w2 * u2h(av.y) + a23;
        }

        // LeakyReLU(0.1) = max(x, 0.1*x)
        h2 tenth; tenth.x = (_Float16)0.1f; tenth.y = (_Float16)0.1f;
        a01 = __builtin_elementwise_max(a01, a01 * tenth);
        a23 = __builtin_elementwise_max(a23, a23 * tenth);

        uint2 r; r.x = h2u(a01); r.y = h2u(a23);
        dst[n] = r;
    }
}

// ---- transpose-out: act f16 [NG][TN][CPG] -> out f32 [B,N] ----
__global__ __launch_bounds__(256) void k_tout(
    const uint2* __restrict__ act, float* __restrict__ out)
{
    const int g = blockIdx.x;
    const uint2* src = act + (size_t)g * TN;
    float* op0 = out + (size_t)(g * CPG + 0) * TN;
    float* op1 = out + (size_t)(g * CPG + 1) * TN;
    float* op2 = out + (size_t)(g * CPG + 2) * TN;
    float* op3 = out + (size_t)(g * CPG + 3) * TN;
    for (int n = threadIdx.x; n < TN; n += 256) {
        const uint2 v = src[n];
        h2 h;
        h = u2h(v.x); op0[n] = (float)h.x; op1[n] = (float)h.y;
        h = u2h(v.y); op2[n] = (float)h.x; op3[n] = (float)h.y;
    }
}

extern "C" void kernel_launch(void* const* d_in, const int* in_sizes, int n_in,
                              void* d_out, int out_size, void* d_ws, size_t ws_size,
                              hipStream_t stream)
{
    const float* x       = (const float*)d_in[0];   // [B,N]
    const int*   src_idx = (const int*)  d_in[1];   // [LV,N,K]
    const float* weights = (const float*)d_in[2];   // [LV,N,K]
    const float* biases  = (const float*)d_in[3];   // [LV,N]
    float* out = (float*)d_out;                     // [B,N]

    uint2* actA = (uint2*)d_ws;                     // [NG][TN] = 10.24 MB
    uint2* actB = actA + (size_t)NG * TN;           // 10.24 MB
    u32*   pe   = (u32*)(actB + (size_t)NG * TN);   // [LV][PEL] = 2.91 MB

    // pack edges
    {
        const int ne = TLV * TN * TK;
        hipLaunchKernelGGL(k_pack, dim3((ne + 255) / 256), dim3(256), 0, stream,
                           src_idx, weights, pe);
    }
    // x -> actA
    hipLaunchKernelGGL(k_tin, dim3(NG), dim3(256), 0, stream, x, actA);

    uint2* cur = actA;
    uint2* nxt = actB;
    for (int l = 0; l < TLV; ++l) {
        hipLaunchKernelGGL(k_level, dim3(NG), dim3(LT), 0, stream,
                           cur, nxt,
                           pe + (size_t)l * PEL,
                           biases + (size_t)l * TN);
        uint2* tmp = cur; cur = nxt; nxt = tmp;
    }

    hipLaunchKernelGGL(k_tout, dim3(NG), dim3(256), 0, stream, cur, out);
}

// Round 9
// 128.286 us; speedup vs baseline: 1.7328x; 1.4156x over previous
//
#include <hip/hip_runtime.h>

// TopologyNetwork: B=1024, N=5000, K=16, 9 levels.
// R9: KEY INSIGHT — the DAG gather runs over nodes only; batch columns never
// mix. So a block owning col-group g (4 f16 cols) and ALL N nodes is fully
// self-contained across ALL levels. One fused kernel: stage x-slice into LDS,
// run 9 levels ping-ponging between two 40 KB LDS buffers (__syncthreads
// between levels), write final slice to out. No inter-level global traffic,
// no per-level launches/staging/transposes.
//  - edges prepacked [l][panel64][k][lane] u32=(u16 idx|f16 w): coalesced
//    256 B-line loads, L2-resident (2.9 MB total, per-XCD cacheable).
//  - gather = ds_read_b64 (8 B node-row); packed f16x2 FMA accumulate.

#define TB 1024
#define TN 5000
#define TK 16
#define TLV 9
#define CPG 4                   // f16 cols per group (8 B per node-row)
#define NG  (TB / CPG)          // 256 col-groups = grid
#define LT  1024                // threads per block (16 waves)
#define NPANEL ((TN + 63) / 64) // 79 panels of 64 nodes
#define PEL (NPANEL * TK * 64)  // u32 per level in packed-edge array

typedef unsigned int u32;
typedef unsigned short u16;
typedef _Float16 h2 __attribute__((ext_vector_type(2)));

__device__ __forceinline__ h2 u2h(u32 v) { return __builtin_bit_cast(h2, v); }
__device__ __forceinline__ u32 h2u(h2 h) { return __builtin_bit_cast(u32, h); }
__device__ __forceinline__ u32 packf(float a, float b) {
    h2 h; h.x = (_Float16)a; h.y = (_Float16)b;
    return h2u(h);
}

// ---- pack edges: idx i32 + w f32 [l][n][k] -> pe u32 [l][n>>6][k][n&63] ----
__global__ __launch_bounds__(256) void k_pack(
    const int* __restrict__ idx, const float* __restrict__ w,
    u32* __restrict__ pe)
{
    const int j = blockIdx.x * 256 + threadIdx.x;
    if (j < TLV * TN * TK) {
        const int l = j / (TN * TK);
        const int r = j % (TN * TK);
        const int n = r / TK;
        const int k = r % TK;
        h2 hw; hw.x = (_Float16)w[j]; hw.y = (_Float16)0.0f;
        const u32 v = ((u32)idx[j] & 0xffffu) | (h2u(hw) << 16);
        pe[(size_t)l * PEL + (n >> 6) * (TK * 64) + k * 64 + (n & 63)] = v;
    }
}

// ---- fused: transpose-in + 9 levels in LDS + transpose-out ----
__global__ __launch_bounds__(LT) void k_fused(
    const float* __restrict__ x,      // [B,N]
    float* __restrict__ out,          // [B,N]
    const u32* __restrict__ pe,       // [LV][PEL]
    const float* __restrict__ biases) // [LV][TN]
{
    __shared__ uint2 buf[2][TN];      // 2 x 40000 B ping-pong
    const int g = blockIdx.x;
    const int t = threadIdx.x;

    // stage x cols g*4..g*4+3 as f16 rows
    {
        const float* xp0 = x + (size_t)(g * CPG + 0) * TN;
        const float* xp1 = x + (size_t)(g * CPG + 1) * TN;
        const float* xp2 = x + (size_t)(g * CPG + 2) * TN;
        const float* xp3 = x + (size_t)(g * CPG + 3) * TN;
        for (int n = t; n < TN; n += LT) {
            uint2 v;
            v.x = packf(xp0[n], xp1[n]);
            v.y = packf(xp2[n], xp3[n]);
            buf[0][n] = v;
        }
    }
    __syncthreads();

    int cur = 0;
    for (int l = 0; l < TLV; ++l) {
        const u32*   ep_l = pe + (size_t)l * PEL;
        const float* b_l  = biases + (size_t)l * TN;
        for (int n = t; n < TN; n += LT) {
            const u32* ep = ep_l + (n >> 6) * (TK * 64) + (n & 63);
            const float bvf = b_l[n];
            h2 bb; bb.x = (_Float16)bvf; bb.y = (_Float16)bvf;
            h2 a01 = bb, a23 = bb;

            #pragma unroll
            for (int k = 0; k < TK; ++k) {
                const u32 e = ep[k * 64];                  // coalesced 256 B line
                const u32 s = e & 0xffffu;
                const h2 w2 = u2h(__builtin_amdgcn_perm(e, e, 0x03020302u));
                const uint2 av = buf[cur][s];              // ds_read_b64
                a01 = w2 * u2h(av.x) + a01;                // v_pk_fma_f16
                a23 = w2 * u2h(av.y) + a23;
            }

            // LeakyReLU(0.1) = max(x, 0.1*x)
            h2 tenth; tenth.x = (_Float16)0.1f; tenth.y = (_Float16)0.1f;
            a01 = __builtin_elementwise_max(a01, a01 * tenth);
            a23 = __builtin_elementwise_max(a23, a23 * tenth);

            uint2 r; r.x = h2u(a01); r.y = h2u(a23);
            buf[cur ^ 1][n] = r;
        }
        __syncthreads();
        cur ^= 1;
    }

    // write out cols g*4..g*4+3
    {
        float* op0 = out + (size_t)(g * CPG + 0) * TN;
        float* op1 = out + (size_t)(g * CPG + 1) * TN;
        float* op2 = out + (size_t)(g * CPG + 2) * TN;
        float* op3 = out + (size_t)(g * CPG + 3) * TN;
        for (int n = t; n < TN; n += LT) {
            const uint2 v = buf[cur][n];
            h2 h;
            h = u2h(v.x); op0[n] = (float)h.x; op1[n] = (float)h.y;
            h = u2h(v.y); op2[n] = (float)h.x; op3[n] = (float)h.y;
        }
    }
}

extern "C" void kernel_launch(void* const* d_in, const int* in_sizes, int n_in,
                              void* d_out, int out_size, void* d_ws, size_t ws_size,
                              hipStream_t stream)
{
    const float* x       = (const float*)d_in[0];   // [B,N]
    const int*   src_idx = (const int*)  d_in[1];   // [LV,N,K]
    const float* weights = (const float*)d_in[2];   // [LV,N,K]
    const float* biases  = (const float*)d_in[3];   // [LV,N]
    float* out = (float*)d_out;                     // [B,N]

    u32* pe = (u32*)d_ws;                           // [LV][PEL] = 2.91 MB

    // pack edges
    {
        const int ne = TLV * TN * TK;
        hipLaunchKernelGGL(k_pack, dim3((ne + 255) / 256), dim3(256), 0, stream,
                           src_idx, weights, pe);
    }
    // fused 9-level evaluation
    hipLaunchKernelGGL(k_fused, dim3(NG), dim3(LT), 0, stream,
                       x, out, pe, biases);
}